// Round 12
// baseline (352.446 us; speedup 1.0000x reference)
//
#include <hip/hip_runtime.h>
#include <hip/hip_bf16.h>
#include <stdint.h>

#define Bv 128
#define Hv 256
#define INv 19
#define Pv 512
#define Cv 1024
#define NLh 7

typedef __attribute__((ext_vector_type(4))) float floatx4;
typedef __attribute__((ext_vector_type(8))) short shortx8;
typedef __attribute__((ext_vector_type(4))) unsigned int uintx4;

// packed fp32->bf16 (RNE): lo -> bits[15:0], hi -> bits[31:16]
__device__ __forceinline__ unsigned int cvt_pk_bf16(float lo, float hi) {
    unsigned int r;
    asm("v_cvt_pk_bf16_f32 %0, %1, %2" : "=v"(r) : "v"(lo), "v"(hi));
    return r;
}

__device__ __forceinline__ int swz(int r) { return ((r & 7) ^ ((r >> 3) & 7)); }

// LDS-only barrier: orders DS ops, leaves global loads in flight.
#define BAR() do { asm volatile("s_waitcnt lgkmcnt(0)" ::: "memory"); \
                   __builtin_amdgcn_s_barrier(); } while (0)

// ---------------- fused MLP: first + 7 hidden layers, one launch ----------------
__global__ __launch_bounds__(256) void mlp_fused(
    const float* __restrict__ pos, const float* __restrict__ ue,
    const float* __restrict__ bs,  const float* __restrict__ addf,
    const float* __restrict__ attW1, const float* __restrict__ attb1,
    const float* __restrict__ attWh, const float* __restrict__ attbh,
    const float* __restrict__ radW1, const float* __restrict__ radb1,
    const float* __restrict__ radWh, const float* __restrict__ radbh,
    unsigned short* __restrict__ feat)   // bf16 [128][512]
{
    int blk = blockIdx.x;              // 128 blocks
    int net = blk >> 6, bq = blk & 63; // rows 2bq, 2bq+1
    const float* W1 = net ? radW1 : attW1;
    const float* b1 = net ? radb1 : attb1;
    const float* Wh = net ? radWh : attWh;
    const float* bh = net ? radbh : attbh;
    __shared__ float xs[2][INv];
    __shared__ float hr[2][Hv];
    __shared__ float part[4][2][Hv];
    int t = threadIdx.x;
    if (t < 2 * INv) {
        int r = t / INv, k = t - r * INv;
        int b = bq * 2 + r;
        float v;
        if (k < 3) v = pos[b*3 + k];
        else if (k < 5) v = ue[b*2 + (k-3)];
        else if (k < 9) v = bs[b*4 + (k-5)];
        else v = addf[b*10 + (k-9)];
        xs[r][k] = v;
    }
    __syncthreads();
    {
        float a0 = b1[t], a1 = a0;
        #pragma unroll
        for (int k = 0; k < INv; ++k) {
            float w = W1[k*Hv + t];
            a0 += xs[0][k] * w;
            a1 += xs[1][k] * w;
        }
        hr[0][t] = fmaxf(a0, 0.f);
        hr[1][t] = fmaxf(a1, 0.f);
    }
    __syncthreads();
    int half = t >> 6, oq = t & 63;
    for (int layer = 0; layer < NLh; ++layer) {
        const float* W = Wh + (size_t)layer * Hv * Hv;
        const float* Wp = W + (size_t)(half * 64) * Hv + oq * 4;
        floatx4 a0r0 = {0.f,0.f,0.f,0.f}, a1r0 = {0.f,0.f,0.f,0.f};
        floatx4 a0r1 = {0.f,0.f,0.f,0.f}, a1r1 = {0.f,0.f,0.f,0.f};
        #pragma unroll 8
        for (int kk = 0; kk < 64; kk += 2) {
            floatx4 w0 = *reinterpret_cast<const floatx4*>(Wp + (size_t)kk * Hv);
            floatx4 w1 = *reinterpret_cast<const floatx4*>(Wp + (size_t)(kk+1) * Hv);
            float h00 = hr[0][half*64 + kk], h01 = hr[0][half*64 + kk + 1];
            float h10 = hr[1][half*64 + kk], h11 = hr[1][half*64 + kk + 1];
            a0r0 += w0 * h00; a1r0 += w1 * h01;
            a0r1 += w0 * h10; a1r1 += w1 * h11;
        }
        floatx4 r0 = a0r0 + a1r0, r1 = a0r1 + a1r1;
        *reinterpret_cast<floatx4*>(&part[half][0][oq*4]) = r0;
        *reinterpret_cast<floatx4*>(&part[half][1][oq*4]) = r1;
        __syncthreads();
        int r = t >> 7, o2 = (t & 127) * 2;
        const float* bias = bh + layer * Hv;
        float s0 = part[0][r][o2]   + part[1][r][o2]   + part[2][r][o2]   + part[3][r][o2]   + bias[o2];
        float s1 = part[0][r][o2+1] + part[1][r][o2+1] + part[2][r][o2+1] + part[3][r][o2+1] + bias[o2+1];
        s0 = fmaxf(s0, 0.f); s1 = fmaxf(s1, 0.f);
        if (layer == NLh - 1) {
            *reinterpret_cast<unsigned int*>(
                feat + (size_t)(bq*2 + r) * Pv + net*Hv + o2) = cvt_pk_bf16(s0, s1);
        } else {
            hr[r][o2] = s0; hr[r][o2+1] = s1;
        }
        __syncthreads();
    }
}

// ---------------- Prism: column-partitioned waves, W direct-to-register ----------------
// Wave w owns output cols [w*32, w*32+32). W[:, slice] read ONCE from global
// straight into registers (no LDS, no barriers, no staging VGPRs) -> the
// K-loops are pure VMEM+MFMA per-wave code; 8 independent waves self-stagger.
// LDS: h1 (64KB) + subws (4KB); exactly 2 sync points in the kernel.

// one B-fragment: 8 fp32 column loads (4x64B segments/instr; n-pair fills lines)
__device__ __forceinline__ shortx8 wfrag(const float* __restrict__ Wc,
                                         int kbase, int o, int l) {
    const float* p = Wc + (size_t)(kbase + (l >> 4) * 8) * Hv + o + (l & 15);
    float a0 = p[0*Hv], a1 = p[1*Hv], a2 = p[2*Hv], a3 = p[3*Hv];
    float a4 = p[4*Hv], a5 = p[5*Hv], a6 = p[6*Hv], a7 = p[7*Hv];
    uintx4 v = { cvt_pk_bf16(a0, a1), cvt_pk_bf16(a2, a3),
                 cvt_pk_bf16(a4, a5), cvt_pk_bf16(a6, a7) };
    shortx8 r;
    __builtin_memcpy(&r, &v, 16);
    return r;
}

__global__ __launch_bounds__(512, 1) void prism_kernel(
    const unsigned short* __restrict__ feat,
    const float* __restrict__ W1, const float* __restrict__ b1,
    const float* __restrict__ W2, const float* __restrict__ b2,
    const float* __restrict__ W3, const float* __restrict__ b3,
    float* __restrict__ out)
{
    __shared__ __align__(16) char h1[65536];     // bf16 [128][256] swizzled
    __shared__ float subws[8 * Bv];              // per-wave row partials

    const int tid = threadIdx.x;
    const int l = tid & 63;
    const int w = tid >> 6;          // wave id = column slice
    const int c = blockIdx.x;
    const int ob = w * 32;           // this wave's o-base
    const float* W1c = W1 + (size_t)c * (Pv * Hv);
    const float* W2c = W2 + (size_t)c * (Hv * Hv);

    floatx4 acc[8][2];
    #pragma unroll
    for (int m = 0; m < 8; ++m) {
        acc[m][0] = (floatx4){0.f, 0.f, 0.f, 0.f};
        acc[m][1] = (floatx4){0.f, 0.f, 0.f, 0.f};
    }

    // ---- L1: C[128,256] += feat[128,512] x W1[512,256], 16 k-steps of 32 ----
    #pragma unroll
    for (int u = 0; u < 16; ++u) {
        shortx8 af[8];
        #pragma unroll
        for (int m = 0; m < 8; ++m) {
            int row = m * 16 + (l & 15);
            af[m] = *reinterpret_cast<const shortx8*>(
                feat + (size_t)row * Pv + u * 32 + (l >> 4) * 8);
        }
        shortx8 bf0 = wfrag(W1c, u * 32, ob, l);
        shortx8 bf1 = wfrag(W1c, u * 32, ob + 16, l);
        #pragma unroll
        for (int m = 0; m < 8; ++m) {
            acc[m][0] = __builtin_amdgcn_mfma_f32_16x16x32_bf16(af[m], bf0, acc[m][0], 0, 0, 0);
            acc[m][1] = __builtin_amdgcn_mfma_f32_16x16x32_bf16(af[m], bf1, acc[m][1], 0, 0, 0);
        }
    }

    // ---- h1 epilogue: relu(acc+b1) -> LDS bf16 swizzled ----
    {
        float bias1v[2] = { b1[c*Hv + ob + (l & 15)], b1[c*Hv + ob + 16 + (l & 15)] };
        #pragma unroll
        for (int m = 0; m < 8; ++m) {
            #pragma unroll
            for (int n = 0; n < 2; ++n) {
                int o = ob + n * 16 + (l & 15);
                #pragma unroll
                for (int jj = 0; jj < 4; ++jj) {
                    int row = m * 16 + (l >> 4) * 4 + jj;
                    float v = fmaxf(acc[m][n][jj] + bias1v[n], 0.f);
                    *(unsigned short*)(h1 + row*512 + ((o*2) ^ (swz(row) << 4))) =
                        (unsigned short)(cvt_pk_bf16(v, v) & 0xffffu);
                }
            }
        }
    }
    BAR();

    #pragma unroll
    for (int m = 0; m < 8; ++m) {
        acc[m][0] = (floatx4){0.f, 0.f, 0.f, 0.f};
        acc[m][1] = (floatx4){0.f, 0.f, 0.f, 0.f};
    }

    // ---- L2: C2[128,256] += h1[128,256] x W2[256,256], 8 k-steps of 32 ----
    #pragma unroll
    for (int u = 0; u < 8; ++u) {
        shortx8 af[8];
        #pragma unroll
        for (int m = 0; m < 8; ++m) {
            int row = m * 16 + (l & 15);
            int k2 = u * 32 + (l >> 4) * 8;
            af[m] = *reinterpret_cast<const shortx8*>(
                h1 + row*512 + ((k2*2) ^ (swz(row) << 4)));
        }
        shortx8 bf0 = wfrag(W2c, u * 32, ob, l);
        shortx8 bf1 = wfrag(W2c, u * 32, ob + 16, l);
        #pragma unroll
        for (int m = 0; m < 8; ++m) {
            acc[m][0] = __builtin_amdgcn_mfma_f32_16x16x32_bf16(af[m], bf0, acc[m][0], 0, 0, 0);
            acc[m][1] = __builtin_amdgcn_mfma_f32_16x16x32_bf16(af[m], bf1, acc[m][1], 0, 0, 0);
        }
    }

    // ---- L3: sub[row] = relu(h2)·W3 + b3 over this wave's 32 cols ----
    {
        float bias2v[2] = { b2[c*Hv + ob + (l & 15)], b2[c*Hv + ob + 16 + (l & 15)] };
        float w3v[2]    = { W3[c*Hv + ob + (l & 15)], W3[c*Hv + ob + 16 + (l & 15)] };
        float p[8][4];
        #pragma unroll
        for (int m = 0; m < 8; ++m)
            #pragma unroll
            for (int jj = 0; jj < 4; ++jj) {
                float s = fmaxf(acc[m][0][jj] + bias2v[0], 0.f) * w3v[0]
                        + fmaxf(acc[m][1][jj] + bias2v[1], 0.f) * w3v[1];
                p[m][jj] = s;
            }
        #pragma unroll
        for (int m = 0; m < 8; ++m)
            #pragma unroll
            for (int jj = 0; jj < 4; ++jj) {
                p[m][jj] += __shfl_xor(p[m][jj], 1, 64);
                p[m][jj] += __shfl_xor(p[m][jj], 2, 64);
                p[m][jj] += __shfl_xor(p[m][jj], 4, 64);
                p[m][jj] += __shfl_xor(p[m][jj], 8, 64);
            }
        if ((l & 15) == 0) {
            #pragma unroll
            for (int m = 0; m < 8; ++m)
                #pragma unroll
                for (int jj = 0; jj < 4; ++jj)
                    subws[w * Bv + m*16 + (l >> 4)*4 + jj] = p[m][jj];
        }
    }
    BAR();
    if (tid < Bv) {
        float s = b3[c];
        #pragma unroll
        for (int ww = 0; ww < 8; ++ww) s += subws[ww * Bv + tid];
        out[(size_t)tid * Cv + c] = s;
    }
}

// ---------------- mimo epilogue ----------------

__global__ __launch_bounds__(256) void mimo_kernel(
    const float* __restrict__ sub, const float* __restrict__ mW,
    const float* __restrict__ mB, float* __restrict__ out)
{
    int b = blockIdx.x;
    int t = threadIdx.x;
    float s = 0.f;
    #pragma unroll
    for (int j = 0; j < 4; ++j) s += sub[b*Cv + t + j*256];
    #pragma unroll
    for (int m = 1; m < 64; m <<= 1) s += __shfl_xor(s, m, 64);
    __shared__ float red[4];
    if ((t & 63) == 0) red[t >> 6] = s;
    __syncthreads();
    if (t < 8) {
        float mean = (red[0] + red[1] + red[2] + red[3]) * (1.0f / 1024.0f);
        out[Bv * Cv + b*8 + t] = mean * mW[t] + mB[t];
    }
}

// ---------------- launch ----------------

extern "C" void kernel_launch(void* const* d_in, const int* in_sizes, int n_in,
                              void* d_out, int out_size, void* d_ws, size_t ws_size,
                              hipStream_t stream) {
    (void)in_sizes; (void)n_in; (void)out_size; (void)ws_size;
    const float* pos   = (const float*)d_in[0];
    const float* ue    = (const float*)d_in[1];
    const float* bsant = (const float*)d_in[2];
    const float* addf  = (const float*)d_in[3];
    const float* attW1 = (const float*)d_in[4];
    const float* attb1 = (const float*)d_in[5];
    const float* attWh = (const float*)d_in[6];
    const float* attbh = (const float*)d_in[7];
    const float* radW1 = (const float*)d_in[8];
    const float* radb1 = (const float*)d_in[9];
    const float* radWh = (const float*)d_in[10];
    const float* radbh = (const float*)d_in[11];
    const float* pW1   = (const float*)d_in[12];
    const float* pb1   = (const float*)d_in[13];
    const float* pW2   = (const float*)d_in[14];
    const float* pb2   = (const float*)d_in[15];
    const float* pW3   = (const float*)d_in[16];
    const float* pb3   = (const float*)d_in[17];
    const float* mW    = (const float*)d_in[18];
    const float* mB    = (const float*)d_in[19];
    float* out = (float*)d_out;

    unsigned short* feat = (unsigned short*)d_ws;   // [128][512] bf16

    mlp_fused<<<128, 256, 0, stream>>>(pos, ue, bsant, addf,
                                       attW1, attb1, attWh, attbh,
                                       radW1, radb1, radWh, radbh, feat);
    prism_kernel<<<Cv, 512, 0, stream>>>(feat, pW1, pb1, pW2, pb2, pW3, pb3, out);
    mimo_kernel<<<Bv, 256, 0, stream>>>(out, mW, mB, out);
}